// Round 8
// baseline (208.380 us; speedup 1.0000x reference)
//
#include <hip/hip_runtime.h>
#include <hip/hip_bf16.h>
#include <math.h>

#define NEG_SLOPE 0.2f
// wave-internal LDS ordering: each wave owns a private LDS slice, so a plain
// lgkmcnt drain orders its own ds ops; no __syncthreads (degrees diverge).
#define LDS_FENCE() asm volatile("s_waitcnt lgkmcnt(0)" ::: "memory")

// ===================== partition-segment CSR build (dst-indexed) =====================
#define CSR_NB 128
#define CSR_CAP 2048

// fp32 -> bf16 with round-to-nearest-even (finite inputs)
__device__ __forceinline__ ushort f2bf(float f) {
    uint x = __float_as_uint(f);
    x += 0x7fffu + ((x >> 16) & 1u);
    return (ushort)(x >> 16);
}
__device__ __forceinline__ float bf2f(ushort u) {
    return __uint_as_float((uint)u << 16);
}
// SGPR broadcast of lane l's value (v_readlane_b32): SALU-speed, no LDS/SMEM.
__device__ __forceinline__ float rdlane(float v, int l) {
    return __int_as_float(__builtin_amdgcn_readlane(__float_as_int(v), l));
}

// ---------- GEMM body: Cb[n,0:256] = bf16(X[n,:] @ W), fused attention-logit epilogue ----
// One block = 16 rows x 256 cols, 256 thr = 4 waves, 4 rows/wave, 4 cols/thread.
// Round-7 post-mortem: W-LDS staging alone was null -> the stall was the inner-loop
// wave-uniform X loads (SMEM) mixing with ds_reads in lgkmcnt, forcing full drains.
// Now X never touches memory in the k-loop: per 32-k tile each lane holds one X
// element per row (xs[4], loaded coalesced BEFORE the staging barrier), and the
// inner loop broadcasts via v_readlane (SGPR operand into v_fma). Inner loop =
// {ds_read_b128 x4 + readlane x16 + fma x64} per k-group, DS-only waits.
// Numerically identical to prior rounds (same values, same summation order).
template <int K, bool L1HEADS, bool XBF>
__device__ __forceinline__ void gemm_body(float* __restrict__ ws, int bx,
    const void* __restrict__ Xv, const float* __restrict__ W,
    ushort* __restrict__ Cb, const float* __restrict__ a_src,
    const float* __restrict__ a_dst, float* __restrict__ als,
    float* __restrict__ ald, int N) {
    int t = threadIdx.x;
    int lane = t & 63, wave = t >> 6;
    int n0 = bx * 16 + wave * 4;
    const size_t rowbytes = (size_t)K * (XBF ? 2 : 4);
    const char* Xr[4];
#pragma unroll
    for (int rr = 0; rr < 4; ++rr) {
        int r = min(n0 + rr, N - 1);                       // clamp: tail-safe, uniform
        Xr[rr] = (const char*)Xv + (size_t)__builtin_amdgcn_readfirstlane(r) * rowbytes;
    }
    int kl = lane & 31;                                    // this lane's k-slot in tile
    float4 acc[4] = {};
    for (int kt = 0; kt < K; kt += 32) {
        // per-lane X for this tile: one element per row, coalesced, issued early
        float xs[4];
#pragma unroll
        for (int rr = 0; rr < 4; ++rr) {
            if (XBF) xs[rr] = bf2f(*(const ushort*)(Xr[rr] + (size_t)(kt + kl) * 2));
            else     xs[rr] = *(const float*)(Xr[rr] + (size_t)(kt + kl) * 4);
        }
        // stage W[kt..kt+32)[0..256): 2048 float4, 8 per thread, fully coalesced
        const float4* Wg = (const float4*)(W + (size_t)kt * 256);
        float4* wsv = (float4*)ws;
#pragma unroll
        for (int i = 0; i < 8; ++i) wsv[t + i * 256] = Wg[t + i * 256];
        __syncthreads();
#pragma unroll 4
        for (int kk = 0; kk < 32; kk += 4) {
            float4 w0 = *(const float4*)&ws[(size_t)(kk + 0) * 256 + lane * 4];
            float4 w1 = *(const float4*)&ws[(size_t)(kk + 1) * 256 + lane * 4];
            float4 w2 = *(const float4*)&ws[(size_t)(kk + 2) * 256 + lane * 4];
            float4 w3 = *(const float4*)&ws[(size_t)(kk + 3) * 256 + lane * 4];
#pragma unroll
            for (int rr = 0; rr < 4; ++rr) {
                float x0 = rdlane(xs[rr], kk + 0);
                float x1 = rdlane(xs[rr], kk + 1);
                float x2 = rdlane(xs[rr], kk + 2);
                float x3 = rdlane(xs[rr], kk + 3);
                acc[rr].x = fmaf(x0, w0.x, acc[rr].x);
                acc[rr].y = fmaf(x0, w0.y, acc[rr].y);
                acc[rr].z = fmaf(x0, w0.z, acc[rr].z);
                acc[rr].w = fmaf(x0, w0.w, acc[rr].w);
                acc[rr].x = fmaf(x1, w1.x, acc[rr].x);
                acc[rr].y = fmaf(x1, w1.y, acc[rr].y);
                acc[rr].z = fmaf(x1, w1.z, acc[rr].z);
                acc[rr].w = fmaf(x1, w1.w, acc[rr].w);
                acc[rr].x = fmaf(x2, w2.x, acc[rr].x);
                acc[rr].y = fmaf(x2, w2.y, acc[rr].y);
                acc[rr].z = fmaf(x2, w2.z, acc[rr].z);
                acc[rr].w = fmaf(x2, w2.w, acc[rr].w);
                acc[rr].x = fmaf(x3, w3.x, acc[rr].x);
                acc[rr].y = fmaf(x3, w3.y, acc[rr].y);
                acc[rr].z = fmaf(x3, w3.z, acc[rr].z);
                acc[rr].w = fmaf(x3, w3.w, acc[rr].w);
            }
        }
        __syncthreads();   // WAR: all reads done before next tile's staging
    }
    if (n0 >= N) return;   // after all barriers: safe
    // epilogue: store bf16 C tile + fp32 attention logits.
    // L1HEADS: head h = lane>>2 owns cols [h*16,h*16+16); (lane>>2)*16+(lane&3)*4 == lane*4
    float4 asv = *(const float4*)(a_src + lane * 4);
    float4 adv = *(const float4*)(a_dst + lane * 4);
#pragma unroll
    for (int rr = 0; rr < 4; ++rr) {
        int n = n0 + rr;               // wave-uniform
        if (n >= N) break;
        ushort4 u;
        u.x = f2bf(acc[rr].x); u.y = f2bf(acc[rr].y);
        u.z = f2bf(acc[rr].z); u.w = f2bf(acc[rr].w);
        *(ushort4*)(Cb + (size_t)n * 256 + lane * 4) = u;
        float s = acc[rr].x * asv.x + acc[rr].y * asv.y + acc[rr].z * asv.z + acc[rr].w * asv.w;
        float d = acc[rr].x * adv.x + acc[rr].y * adv.y + acc[rr].z * adv.z + acc[rr].w * adv.w;
        if (L1HEADS) {
            s += __shfl_xor(s, 1); s += __shfl_xor(s, 2);
            d += __shfl_xor(d, 1); d += __shfl_xor(d, 2);
            if ((lane & 3) == 0) {
                als[n * 16 + (lane >> 2)] = s;
                ald[n * 16 + (lane >> 2)] = d;
            }
        } else {
#pragma unroll
            for (int off = 1; off <= 32; off <<= 1) {
                s += __shfl_xor(s, off);
                d += __shfl_xor(d, off);
            }
            if (lane == 0) { als[n] = s; ald[n] = d; }
        }
    }
}

// ---------- fat kernel: CSR count+reserve+scatter UNION gemm1 ----------
__global__ __launch_bounds__(256) void k_scatter_gemm1(
    const int* __restrict__ ei, int E, int N, int NP, int CE,
    int* __restrict__ gcount, int* __restrict__ tmp,
    const float* __restrict__ X, const float* __restrict__ W1, ushort* __restrict__ A,
    const float* __restrict__ as1, const float* __restrict__ ad1,
    float* __restrict__ als1, float* __restrict__ ald1) {
    __shared__ float smem[32 * 256];   // 32KB: gemm W-tile; aliased as hist lhist
    if (blockIdx.x < CSR_NB) {
        int* lhist = (int*)smem;
        int t = threadIdx.x, b = blockIdx.x;
        for (int p = t; p < 384; p += 256) lhist[p] = 0;
        __syncthreads();
        int Etot = E + N;
        int e0 = b * CE, e1 = min(Etot, e0 + CE);
        for (int e = e0 + t; e < e1; e += 256) {
            int d = (e < E) ? ei[E + e] : (e - E);
            atomicAdd(&lhist[d >> 5], 1);
        }
        __syncthreads();
        for (int p = t; p < NP; p += 256) {
            int c = lhist[p];
            lhist[p] = c ? atomicAdd(&gcount[p], c) : 0;   // reserve range; reuse as cursor
        }
        __syncthreads();
        for (int e = e0 + t; e < e1; e += 256) {
            int s, d;
            if (e < E) { s = ei[e]; d = ei[E + e]; } else { s = d = e - E; }
            int p = d >> 5;
            int pos = atomicAdd(&lhist[p], 1);             // LDS atomic: fast
            tmp[p * CSR_CAP + min(pos, CSR_CAP - 1)] = (s << 5) | (d & 31);
        }
    } else {
        gemm_body<128, true, false>(smem, blockIdx.x - CSR_NB, X, W1, A, as1, ad1, als1, ald1, N);
    }
}

__global__ __launch_bounds__(256) void k_gemm2(
    const ushort* __restrict__ Xb, const float* __restrict__ W, ushort* __restrict__ Cb,
    const float* __restrict__ as2, const float* __restrict__ ad2,
    float* __restrict__ als, float* __restrict__ ald, int N) {
    __shared__ float smem[32 * 256];   // 32KB W-tile
    gemm_body<256, false, true>(smem, blockIdx.x, Xb, W, Cb, as2, ad2, als, ald, N);
}

// ---------- CSR finalize: one block per partition -> rowse {start,end} + col ----------
__global__ __launch_bounds__(256) void k_csr_final(const int* __restrict__ tmp,
                                                   const int* __restrict__ gcount,
                                                   int2* __restrict__ rowse,
                                                   int* __restrict__ col, int N) {
    __shared__ int dcnt[32], dcur[32];
    int t = threadIdx.x, p = blockIdx.x;
    int base = p * CSR_CAP;
    int cnt = min(gcount[p], CSR_CAP);
    if (t < 32) dcnt[t] = 0;
    __syncthreads();
    for (int i = t; i < cnt; i += 256) atomicAdd(&dcnt[tmp[base + i] & 31], 1);
    __syncthreads();
    if (t < 32) {
        int v = dcnt[t];
        int x = v;
#pragma unroll
        for (int off = 1; off < 32; off <<= 1) {
            int u = __shfl_up(x, off);
            if (t >= off) x += u;
        }
        int excl = x - v;
        dcur[t] = excl;
        int dst = (p << 5) + t;
        if (dst < N) rowse[dst] = make_int2(base + excl, base + excl + v);
    }
    __syncthreads();
    for (int i = t; i < cnt; i += 256) {
        int v = tmp[base + i];
        int pos = atomicAdd(&dcur[v & 31], 1);
        col[base + pos] = v >> 5;
    }
}

// ---------- fused GAT gather, 1 head: one wave per node, bf16 rows, 8-deep MLP ----
__global__ __launch_bounds__(256) void k_gather_h1(
    const int2* __restrict__ rowse, const int* __restrict__ col,
    const ushort* __restrict__ Hb, const float* __restrict__ als,
    const float* __restrict__ ald, const float* __restrict__ bias,
    ushort* __restrict__ outb, int N) {
    int wave = threadIdx.x >> 6, lane = threadIdx.x & 63;
    int n = blockIdx.x * 4 + wave;
    if (n >= N) return;
    int2 se2 = rowse[n];
    int start = se2.x, end = se2.y;
    float aldv = ald[n];
    float4 acc = {0.f, 0.f, 0.f, 0.f};
    float swsum = 0.f;
    const ushort* Hl = Hb + lane * 4;
    for (int base = start; base < end; base += 64) {
        int len = min(64, end - base);
        int s_r = 0;
        float w_r = 0.f;
        if (lane < len) {
            s_r = col[base + lane];
            float v = als[s_r] + aldv;
            v = v >= 0.f ? v : NEG_SLOPE * v;
            w_r = __expf(v);
        }
        swsum += w_r;
        int len8 = (len + 7) & ~7;
        for (int e = 0; e < len8; e += 8) {
            const ushort* hp[8];
            float we[8];
#pragma unroll
            for (int j = 0; j < 8; ++j) {
                hp[j] = Hl + (size_t)__shfl(s_r, e + j) * 256;
                we[j] = __shfl(w_r, e + j);
            }
            ushort4 uv[8];
#pragma unroll
            for (int j = 0; j < 8; ++j) uv[j] = *(const ushort4*)hp[j];
#pragma unroll
            for (int j = 0; j < 8; ++j) {
                acc.x = fmaf(we[j], bf2f(uv[j].x), acc.x);
                acc.y = fmaf(we[j], bf2f(uv[j].y), acc.y);
                acc.z = fmaf(we[j], bf2f(uv[j].z), acc.z);
                acc.w = fmaf(we[j], bf2f(uv[j].w), acc.w);
            }
        }
    }
#pragma unroll
    for (int off = 32; off >= 1; off >>= 1) swsum += __shfl_xor(swsum, off);
    float inv = 1.0f / swsum;
    float4 bv = *(const float4*)(bias + lane * 4);
    ushort4 o;
    o.x = f2bf(fmaf(acc.x, inv, bv.x));
    o.y = f2bf(fmaf(acc.y, inv, bv.y));
    o.z = f2bf(fmaf(acc.z, inv, bv.z));
    o.w = f2bf(fmaf(acc.w, inv, bv.w));
    *(ushort4*)(outb + (size_t)n * 256 + lane * 4) = o;
}

// ---------- fused GAT gather, 16 heads x 16ch: bf16 rows, reg-broadcast src ----
__global__ __launch_bounds__(256) void k_gather_h16(
    const int2* __restrict__ rowse, const int* __restrict__ col,
    const ushort* __restrict__ Hb, const float* __restrict__ als,
    const float* __restrict__ ald, const float* __restrict__ bias,
    ushort* __restrict__ outb, int N) {
    __shared__ float w_lds[4][64 * 16];
    int wave = threadIdx.x >> 6, lane = threadIdx.x & 63;
    int n = blockIdx.x * 4 + wave;
    if (n >= N) return;
    int2 se2 = rowse[n];
    int start = se2.x, end = se2.y;
    int hq = lane & 15;                // head this lane computes logits for
    int eq = lane >> 4;                // edge sub-slot 0..3
    float aldW = ald[n * 16 + hq];
    float4 acc = {0.f, 0.f, 0.f, 0.f};
    float swp = 0.f;                   // partial w-sum for head hq
    const ushort* Hl = Hb + lane * 4;
    for (int base = start; base < end; base += 64) {
        int len = min(64, end - base);
        int s_r = (lane < len) ? col[base + lane] : 0;
#pragma unroll
        for (int k = 0; k < 16; ++k) {
            int esub = (k << 2) + eq;
            int s = __shfl(s_r, esub);
            float w = 0.f;
            if (esub < len) {
                float v = als[s * 16 + hq] + aldW;
                v = v >= 0.f ? v : NEG_SLOPE * v;
                w = __expf(v);
            }
            w_lds[wave][(esub << 4) + hq] = w;   // every slot written (0 for pads)
            swp += w;
        }
        LDS_FENCE();
        int len8 = (len + 7) & ~7;
        for (int e = 0; e < len8; e += 8) {
            const ushort* hp[8];
            float we[8];
#pragma unroll
            for (int j = 0; j < 8; ++j) {
                hp[j] = Hl + (size_t)__shfl(s_r, e + j) * 256;
                we[j] = w_lds[wave][((e + j) << 4) + (lane >> 2)];
            }
            ushort4 uv[8];
#pragma unroll
            for (int j = 0; j < 8; ++j) uv[j] = *(const ushort4*)hp[j];
#pragma unroll
            for (int j = 0; j < 8; ++j) {
                acc.x = fmaf(we[j], bf2f(uv[j].x), acc.x);
                acc.y = fmaf(we[j], bf2f(uv[j].y), acc.y);
                acc.z = fmaf(we[j], bf2f(uv[j].z), acc.z);
                acc.w = fmaf(we[j], bf2f(uv[j].w), acc.w);
            }
        }
        LDS_FENCE();   // WAR guard: next chunk's weight phase overwrites w_lds
    }
    // head totals live on lanes sharing (lane&15)
    swp += __shfl_xor(swp, 16);
    swp += __shfl_xor(swp, 32);
    float inv = 1.0f / __shfl(swp, lane >> 2);   // head of this lane's col group
    float4 bv = *(const float4*)(bias + lane * 4);
    ushort4 o;
    o.x = f2bf(fmaxf(fmaf(acc.x, inv, bv.x), 0.f));
    o.y = f2bf(fmaxf(fmaf(acc.y, inv, bv.y), 0.f));
    o.z = f2bf(fmaxf(fmaf(acc.z, inv, bv.z), 0.f));
    o.w = f2bf(fmaxf(fmaf(acc.w, inv, bv.w), 0.f));
    *(ushort4*)(outb + (size_t)n * 256 + lane * 4) = o;
}

// ---------- fused mean-pool + final linear: one block per graph (B is bf16) ----------
__device__ __forceinline__ int lower_bound_i(const int* __restrict__ a, int n, int v) {
    int lo = 0, hi = n;
    while (lo < hi) {
        int mid = (lo + hi) >> 1;
        if (a[mid] < v) lo = mid + 1; else hi = mid;
    }
    return lo;
}

__global__ __launch_bounds__(1024) void k_pool_final(const ushort* __restrict__ Bb,
                                                     const int* __restrict__ batch,
                                                     const float* __restrict__ lw,
                                                     const float* __restrict__ lb,
                                                     float* __restrict__ out,
                                                     int N, int L) {
    __shared__ float psum[4][256];
    __shared__ float csum[256];
    int t = threadIdx.x;
    int c = t & 255, q = t >> 8;
    int g = blockIdx.x;
    int lo = lower_bound_i(batch, N, g);
    int hi = lower_bound_i(batch, N, g + 1);
    int len = hi - lo;
    int per = (len + 3) >> 2;
    int s0 = lo + q * per, s1 = min(hi, s0 + per);
    float acc = 0.f;
    for (int r = s0; r < s1; ++r) acc += bf2f(Bb[(size_t)r * 256 + c]);
    psum[q][c] = acc;
    __syncthreads();
    if (t < 256) csum[t] = psum[0][t] + psum[1][t] + psum[2][t] + psum[3][t];
    __syncthreads();
    int wave = t >> 6, lane = t & 63;
    if (wave < L) {
        int l = wave;
        float a = csum[lane] * lw[lane * L + l] +
                  csum[lane + 64] * lw[(lane + 64) * L + l] +
                  csum[lane + 128] * lw[(lane + 128) * L + l] +
                  csum[lane + 192] * lw[(lane + 192) * L + l];
#pragma unroll
        for (int off = 32; off >= 1; off >>= 1) a += __shfl_xor(a, off);
        if (lane == 0) out[g * L + l] = a / fmaxf((float)len, 1.0f) + lb[l];
    }
}

extern "C" void kernel_launch(void* const* d_in, const int* in_sizes, int n_in,
                              void* d_out, int out_size, void* d_ws, size_t ws_size,
                              hipStream_t stream) {
    const float* x   = (const float*)d_in[0];
    const int*   ei  = (const int*)d_in[1];
    const int*   bat = (const int*)d_in[2];
    const float* W1  = (const float*)d_in[3];
    const float* as1 = (const float*)d_in[4];
    const float* ad1 = (const float*)d_in[5];
    const float* b1  = (const float*)d_in[6];
    const float* W2  = (const float*)d_in[7];
    const float* as2 = (const float*)d_in[8];
    const float* ad2 = (const float*)d_in[9];
    const float* b2  = (const float*)d_in[10];
    const float* lw  = (const float*)d_in[11];
    const float* lb  = (const float*)d_in[12];
    float* out = (float*)d_out;

    const int N = in_sizes[2];        // 10000
    const int E = in_sizes[1] / 2;    // 320000
    const int G = 64, L = 10;
    const int Etot = E + N;
    const int NP = (N + 31) >> 5;     // partitions of 32 dsts (313)
    const int CE = (Etot + CSR_NB - 1) / CSR_NB;

    // workspace layout (A/B keep fp32-sized slots; used as bf16)
    float* A    = (float*)d_ws;              // [N,256] bf16 h1 then h2 (as ushort)
    float* B    = A + (size_t)N * 256;       // [N,256] bf16 out1 then out2 (as ushort)
    float* als1 = B + (size_t)N * 256;       // [N,16]
    float* ald1 = als1 + (size_t)N * 16;
    float* als2 = ald1 + (size_t)N * 16;     // [N]
    float* ald2 = als2 + N;
    int2* rowse = (int2*)(ald2 + N);         // [N] {start,end}
    int* col    = (int*)(rowse + N);         // [NP*CAP] strided segments
    int* tmp    = col + (size_t)NP * CSR_CAP;// [NP*CAP] packed (src<<5)|d5
    int* gcount = tmp + (size_t)NP * CSR_CAP;// [NP]
    ushort* Abf = (ushort*)A;
    ushort* Bbf = (ushort*)B;

    const int BS = 256;
    auto nb = [](int n, int b) { return (n + b - 1) / b; };
    int nodes4 = nb(N, 4);
    int rows16 = nb(N, 16);

    // ---- zero partition counters (1.3KB), then fused CSR-scatter + gemm1 ----
    hipMemsetAsync(gcount, 0, NP * sizeof(int), stream);
    k_scatter_gemm1<<<CSR_NB + rows16, BS, 0, stream>>>(ei, E, N, NP, CE, gcount, tmp,
                                                        x, W1, Abf, as1, ad1, als1, ald1);
    k_csr_final<<<NP, BS, 0, stream>>>(tmp, gcount, rowse, col, N);

    // ---- layer 1 aggregate ----
    k_gather_h16<<<nodes4, BS, 0, stream>>>(rowse, col, Abf, als1, ald1, b1, Bbf, N);

    // ---- layer 2 ----
    k_gemm2<<<rows16, BS, 0, stream>>>(Bbf, W2, Abf, as2, ad2, als2, ald2, N);
    k_gather_h1<<<nodes4, BS, 0, stream>>>(rowse, col, Abf, als2, ald2, b2, Bbf, N);

    // ---- fused pool + final linear ----
    k_pool_final<<<G, 1024, 0, stream>>>(Bbf, bat, lw, lb, out, N, L);
}

// Round 9
// 191.537 us; speedup vs baseline: 1.0879x; 1.0879x over previous
//
#include <hip/hip_runtime.h>
#include <hip/hip_bf16.h>
#include <math.h>

#define NEG_SLOPE 0.2f
// wave-internal LDS ordering: each wave owns a private LDS slice, so a plain
// lgkmcnt drain orders its own ds ops; no __syncthreads (degrees diverge).
#define LDS_FENCE() asm volatile("s_waitcnt lgkmcnt(0)" ::: "memory")

// ===================== partition-segment CSR build (dst-indexed) =====================
#define CSR_NB 128
#define CSR_CAP 2048
#define WT_NB 64            // W2 transpose-convert blocks riding in the fat kernel

// fp32 -> bf16 with round-to-nearest-even (finite inputs)
__device__ __forceinline__ ushort f2bf(float f) {
    uint x = __float_as_uint(f);
    x += 0x7fffu + ((x >> 16) & 1u);
    return (ushort)(x >> 16);
}
__device__ __forceinline__ float bf2f(ushort u) {
    return __uint_as_float((uint)u << 16);
}

typedef __attribute__((ext_vector_type(8))) short bf16x8v;   // MFMA A/B fragment (4 VGPRs)
typedef __attribute__((ext_vector_type(4))) float f32x4;     // MFMA C/D fragment

// ---------- gemm1 body (round-7 form, best measured): VALU fp32, W staged in LDS ----
// One block = 16 rows x 256 cols, 4 waves, 4 rows/wave, 4 cols/thread. X fp32 via
// wave-uniform (readfirstlane) loads; W k-tiles (32x256 = 32KB) cooperatively staged.
__device__ __forceinline__ void gemm1_body(float* __restrict__ ws, int bx,
    const float* __restrict__ X, const float* __restrict__ W,
    ushort* __restrict__ Cb, const float* __restrict__ a_src,
    const float* __restrict__ a_dst, float* __restrict__ als,
    float* __restrict__ ald, int N) {
    const int K = 128;
    int t = threadIdx.x;
    int lane = t & 63, wave = t >> 6;
    int n0 = bx * 16 + wave * 4;
    const float* Xr[4];
#pragma unroll
    for (int rr = 0; rr < 4; ++rr) {
        int r = min(n0 + rr, N - 1);                       // clamp: tail-safe, uniform
        Xr[rr] = X + (size_t)__builtin_amdgcn_readfirstlane(r) * K;
    }
    float4 acc[4] = {};
    for (int kt = 0; kt < K; kt += 32) {
        const float4* Wg = (const float4*)(W + (size_t)kt * 256);
        float4* wsv = (float4*)ws;
#pragma unroll
        for (int i = 0; i < 8; ++i) wsv[t + i * 256] = Wg[t + i * 256];
        __syncthreads();
#pragma unroll 4
        for (int kk = 0; kk < 32; kk += 4) {
            int k = kt + kk;
            float4 w0 = *(const float4*)&ws[(size_t)(kk + 0) * 256 + lane * 4];
            float4 w1 = *(const float4*)&ws[(size_t)(kk + 1) * 256 + lane * 4];
            float4 w2 = *(const float4*)&ws[(size_t)(kk + 2) * 256 + lane * 4];
            float4 w3 = *(const float4*)&ws[(size_t)(kk + 3) * 256 + lane * 4];
#pragma unroll
            for (int rr = 0; rr < 4; ++rr) {
                float4 xv = *(const float4*)(Xr[rr] + k);
                acc[rr].x = fmaf(xv.x, w0.x, acc[rr].x);
                acc[rr].y = fmaf(xv.x, w0.y, acc[rr].y);
                acc[rr].z = fmaf(xv.x, w0.z, acc[rr].z);
                acc[rr].w = fmaf(xv.x, w0.w, acc[rr].w);
                acc[rr].x = fmaf(xv.y, w1.x, acc[rr].x);
                acc[rr].y = fmaf(xv.y, w1.y, acc[rr].y);
                acc[rr].z = fmaf(xv.y, w1.z, acc[rr].z);
                acc[rr].w = fmaf(xv.y, w1.w, acc[rr].w);
                acc[rr].x = fmaf(xv.z, w2.x, acc[rr].x);
                acc[rr].y = fmaf(xv.z, w2.y, acc[rr].y);
                acc[rr].z = fmaf(xv.z, w2.z, acc[rr].z);
                acc[rr].w = fmaf(xv.z, w2.w, acc[rr].w);
                acc[rr].x = fmaf(xv.w, w3.x, acc[rr].x);
                acc[rr].y = fmaf(xv.w, w3.y, acc[rr].y);
                acc[rr].z = fmaf(xv.w, w3.z, acc[rr].z);
                acc[rr].w = fmaf(xv.w, w3.w, acc[rr].w);
            }
        }
        __syncthreads();   // WAR: all reads done before next tile's staging
    }
    if (n0 >= N) return;   // after all barriers: safe
    // epilogue: bf16 C tile + per-head logits. head h = lane>>2; (lane>>2)*16+(lane&3)*4 == lane*4
    float4 asv = *(const float4*)(a_src + lane * 4);
    float4 adv = *(const float4*)(a_dst + lane * 4);
#pragma unroll
    for (int rr = 0; rr < 4; ++rr) {
        int n = n0 + rr;               // wave-uniform
        if (n >= N) break;
        ushort4 u;
        u.x = f2bf(acc[rr].x); u.y = f2bf(acc[rr].y);
        u.z = f2bf(acc[rr].z); u.w = f2bf(acc[rr].w);
        *(ushort4*)(Cb + (size_t)n * 256 + lane * 4) = u;
        float s = acc[rr].x * asv.x + acc[rr].y * asv.y + acc[rr].z * asv.z + acc[rr].w * asv.w;
        float d = acc[rr].x * adv.x + acc[rr].y * adv.y + acc[rr].z * adv.z + acc[rr].w * adv.w;
        s += __shfl_xor(s, 1); s += __shfl_xor(s, 2);
        d += __shfl_xor(d, 1); d += __shfl_xor(d, 2);
        if ((lane & 3) == 0) {
            als[n * 16 + (lane >> 2)] = s;
            ald[n * 16 + (lane >> 2)] = d;
        }
    }
}

// ---------- fat kernel: CSR scatter UNION W2-transpose-convert UNION gemm1 ----------
__global__ __launch_bounds__(256) void k_scatter_gemm1(
    const int* __restrict__ ei, int E, int N, int NP, int CE,
    int* __restrict__ gcount, int* __restrict__ tmp,
    const float* __restrict__ X, const float* __restrict__ W1, ushort* __restrict__ A,
    const float* __restrict__ as1, const float* __restrict__ ad1,
    float* __restrict__ als1, float* __restrict__ ald1,
    const float* __restrict__ W2, ushort* __restrict__ Wt) {
    __shared__ float smem[32 * 256];   // 32KB: gemm W-tile / hist / transpose tile
    int t = threadIdx.x;
    if (blockIdx.x < CSR_NB) {
        int* lhist = (int*)smem;
        int b = blockIdx.x;
        for (int p = t; p < 384; p += 256) lhist[p] = 0;
        __syncthreads();
        int Etot = E + N;
        int e0 = b * CE, e1 = min(Etot, e0 + CE);
        for (int e = e0 + t; e < e1; e += 256) {
            int d = (e < E) ? ei[E + e] : (e - E);
            atomicAdd(&lhist[d >> 5], 1);
        }
        __syncthreads();
        for (int p = t; p < NP; p += 256) {
            int c = lhist[p];
            lhist[p] = c ? atomicAdd(&gcount[p], c) : 0;   // reserve range; reuse as cursor
        }
        __syncthreads();
        for (int e = e0 + t; e < e1; e += 256) {
            int s, d;
            if (e < E) { s = ei[e]; d = ei[E + e]; } else { s = d = e - E; }
            int p = d >> 5;
            int pos = atomicAdd(&lhist[p], 1);             // LDS atomic: fast
            tmp[p * CSR_CAP + min(pos, CSR_CAP - 1)] = (s << 5) | (d & 31);
        }
    } else if (blockIdx.x < CSR_NB + WT_NB) {
        // transpose-convert W2[256 k][256 j] fp32 -> Wt[256 j][256 k] bf16, 32x32 tiles
        float (*tile)[33] = (float (*)[33])smem;
        int tb = blockIdx.x - CSR_NB;
        int k0 = (tb >> 3) * 32, j0 = (tb & 7) * 32;
        int c = t & 31, i0 = t >> 5;
#pragma unroll
        for (int p = 0; p < 4; ++p) {
            int i = i0 + p * 8;
            tile[i][c] = W2[(size_t)(k0 + i) * 256 + j0 + c];
        }
        __syncthreads();
#pragma unroll
        for (int p = 0; p < 4; ++p) {
            int i = i0 + p * 8;
            Wt[(size_t)(j0 + i) * 256 + k0 + c] = f2bf(tile[c][i]);
        }
    } else {
        gemm1_body(smem, blockIdx.x - CSR_NB - WT_NB, X, W1, A, as1, ad1, als1, ald1, N);
    }
}

// ---------- gemm2 via MFMA: Cb[n,0:256] = bf16(Xb[n,:] @ W2), fused logit epilogue ----
// Block = 16 rows x 256 cols, 4 waves; wave w owns cols [w*64, w*64+64) (4 16-col tiles).
// Fragments (mfma_f32_16x16x32_bf16): A: lane holds X[n0+(lane&15)][ks*32+(lane>>4)*8+j]
// (16B contiguous bf16); B: Wt[col][k] transposed layout makes B-frag 16B contiguous too.
// D: row=(lane>>4)*4+r, col=lane&15 [m89]. K-loop: 8 A-loads + 32 B-loads + 32 MFMA per
// wave, no LDS/barriers. Logits: fp32 acc -> per-row 16-lane shuffle + cross-wave LDS.
__global__ __launch_bounds__(256) void k_gemm2_mfma(
    const ushort* __restrict__ Xb, const ushort* __restrict__ Wt,
    ushort* __restrict__ Cb, const float* __restrict__ as2,
    const float* __restrict__ ad2, float* __restrict__ als,
    float* __restrict__ ald, int N) {
    __shared__ float red[4][16][2];
    int t = threadIdx.x, lane = t & 63, w = t >> 6;
    int n0 = blockIdx.x * 16;
    int l15 = lane & 15, kb = lane >> 4;
    int col0 = w * 64;
    int arow = min(n0 + l15, N - 1);
    const ushort* Xp = Xb + (size_t)arow * 256 + kb * 8;
    f32x4 acc[4] = {f32x4{0,0,0,0}, f32x4{0,0,0,0}, f32x4{0,0,0,0}, f32x4{0,0,0,0}};
#pragma unroll
    for (int ks = 0; ks < 8; ++ks) {
        bf16x8v a = *(const bf16x8v*)(Xp + ks * 32);
#pragma unroll
        for (int tt = 0; tt < 4; ++tt) {
            const ushort* Bp = Wt + (size_t)(col0 + tt * 16 + l15) * 256 + ks * 32 + kb * 8;
            bf16x8v b = *(const bf16x8v*)Bp;
            acc[tt] = __builtin_amdgcn_mfma_f32_16x16x32_bf16(a, b, acc[tt], 0, 0, 0);
        }
    }
    // store D (bf16) + logit partials
#pragma unroll
    for (int r = 0; r < 4; ++r) {
        int n = n0 + kb * 4 + r;
        float s = 0.f, d = 0.f;
#pragma unroll
        for (int tt = 0; tt < 4; ++tt) {
            int col = col0 + tt * 16 + l15;
            float v = acc[tt][r];
            if (n < N) Cb[(size_t)n * 256 + col] = f2bf(v);
            s += v * as2[col];
            d += v * ad2[col];
        }
        s += __shfl_xor(s, 1); s += __shfl_xor(s, 2);
        s += __shfl_xor(s, 4); s += __shfl_xor(s, 8);
        d += __shfl_xor(d, 1); d += __shfl_xor(d, 2);
        d += __shfl_xor(d, 4); d += __shfl_xor(d, 8);
        if (l15 == 0) { red[w][kb * 4 + r][0] = s; red[w][kb * 4 + r][1] = d; }
    }
    __syncthreads();
    if (t < 16) {
        int n = n0 + t;
        if (n < N) {
            als[n] = red[0][t][0] + red[1][t][0] + red[2][t][0] + red[3][t][0];
            ald[n] = red[0][t][1] + red[1][t][1] + red[2][t][1] + red[3][t][1];
        }
    }
}

// ---------- CSR finalize: one block per partition -> rowse {start,end} + col ----------
__global__ __launch_bounds__(256) void k_csr_final(const int* __restrict__ tmp,
                                                   const int* __restrict__ gcount,
                                                   int2* __restrict__ rowse,
                                                   int* __restrict__ col, int N) {
    __shared__ int dcnt[32], dcur[32];
    int t = threadIdx.x, p = blockIdx.x;
    int base = p * CSR_CAP;
    int cnt = min(gcount[p], CSR_CAP);
    if (t < 32) dcnt[t] = 0;
    __syncthreads();
    for (int i = t; i < cnt; i += 256) atomicAdd(&dcnt[tmp[base + i] & 31], 1);
    __syncthreads();
    if (t < 32) {
        int v = dcnt[t];
        int x = v;
#pragma unroll
        for (int off = 1; off < 32; off <<= 1) {
            int u = __shfl_up(x, off);
            if (t >= off) x += u;
        }
        int excl = x - v;
        dcur[t] = excl;
        int dst = (p << 5) + t;
        if (dst < N) rowse[dst] = make_int2(base + excl, base + excl + v);
    }
    __syncthreads();
    for (int i = t; i < cnt; i += 256) {
        int v = tmp[base + i];
        int pos = atomicAdd(&dcur[v & 31], 1);
        col[base + pos] = v >> 5;
    }
}

// ---------- fused GAT gather, 1 head: one wave per node, bf16 rows, 8-deep MLP ----
__global__ __launch_bounds__(256) void k_gather_h1(
    const int2* __restrict__ rowse, const int* __restrict__ col,
    const ushort* __restrict__ Hb, const float* __restrict__ als,
    const float* __restrict__ ald, const float* __restrict__ bias,
    ushort* __restrict__ outb, int N) {
    int wave = threadIdx.x >> 6, lane = threadIdx.x & 63;
    int n = blockIdx.x * 4 + wave;
    if (n >= N) return;
    int2 se2 = rowse[n];
    int start = se2.x, end = se2.y;
    float aldv = ald[n];
    float4 acc = {0.f, 0.f, 0.f, 0.f};
    float swsum = 0.f;
    const ushort* Hl = Hb + lane * 4;
    for (int base = start; base < end; base += 64) {
        int len = min(64, end - base);
        int s_r = 0;
        float w_r = 0.f;
        if (lane < len) {
            s_r = col[base + lane];
            float v = als[s_r] + aldv;
            v = v >= 0.f ? v : NEG_SLOPE * v;
            w_r = __expf(v);
        }
        swsum += w_r;
        int len8 = (len + 7) & ~7;
        for (int e = 0; e < len8; e += 8) {
            const ushort* hp[8];
            float we[8];
#pragma unroll
            for (int j = 0; j < 8; ++j) {
                hp[j] = Hl + (size_t)__shfl(s_r, e + j) * 256;
                we[j] = __shfl(w_r, e + j);
            }
            ushort4 uv[8];
#pragma unroll
            for (int j = 0; j < 8; ++j) uv[j] = *(const ushort4*)hp[j];
#pragma unroll
            for (int j = 0; j < 8; ++j) {
                acc.x = fmaf(we[j], bf2f(uv[j].x), acc.x);
                acc.y = fmaf(we[j], bf2f(uv[j].y), acc.y);
                acc.z = fmaf(we[j], bf2f(uv[j].z), acc.z);
                acc.w = fmaf(we[j], bf2f(uv[j].w), acc.w);
            }
        }
    }
#pragma unroll
    for (int off = 32; off >= 1; off >>= 1) swsum += __shfl_xor(swsum, off);
    float inv = 1.0f / swsum;
    float4 bv = *(const float4*)(bias + lane * 4);
    ushort4 o;
    o.x = f2bf(fmaf(acc.x, inv, bv.x));
    o.y = f2bf(fmaf(acc.y, inv, bv.y));
    o.z = f2bf(fmaf(acc.z, inv, bv.z));
    o.w = f2bf(fmaf(acc.w, inv, bv.w));
    *(ushort4*)(outb + (size_t)n * 256 + lane * 4) = o;
}

// ---------- fused GAT gather, 16 heads x 16ch: bf16 rows, reg-broadcast src ----
__global__ __launch_bounds__(256) void k_gather_h16(
    const int2* __restrict__ rowse, const int* __restrict__ col,
    const ushort* __restrict__ Hb, const float* __restrict__ als,
    const float* __restrict__ ald, const float* __restrict__ bias,
    ushort* __restrict__ outb, int N) {
    __shared__ float w_lds[4][64 * 16];
    int wave = threadIdx.x >> 6, lane = threadIdx.x & 63;
    int n = blockIdx.x * 4 + wave;
    if (n >= N) return;
    int2 se2 = rowse[n];
    int start = se2.x, end = se2.y;
    int hq = lane & 15;                // head this lane computes logits for
    int eq = lane >> 4;                // edge sub-slot 0..3
    float aldW = ald[n * 16 + hq];
    float4 acc = {0.f, 0.f, 0.f, 0.f};
    float swp = 0.f;                   // partial w-sum for head hq
    const ushort* Hl = Hb + lane * 4;
    for (int base = start; base < end; base += 64) {
        int len = min(64, end - base);
        int s_r = (lane < len) ? col[base + lane] : 0;
#pragma unroll
        for (int k = 0; k < 16; ++k) {
            int esub = (k << 2) + eq;
            int s = __shfl(s_r, esub);
            float w = 0.f;
            if (esub < len) {
                float v = als[s * 16 + hq] + aldW;
                v = v >= 0.f ? v : NEG_SLOPE * v;
                w = __expf(v);
            }
            w_lds[wave][(esub << 4) + hq] = w;   // every slot written (0 for pads)
            swp += w;
        }
        LDS_FENCE();
        int len8 = (len + 7) & ~7;
        for (int e = 0; e < len8; e += 8) {
            const ushort* hp[8];
            float we[8];
#pragma unroll
            for (int j = 0; j < 8; ++j) {
                hp[j] = Hl + (size_t)__shfl(s_r, e + j) * 256;
                we[j] = w_lds[wave][((e + j) << 4) + (lane >> 2)];
            }
            ushort4 uv[8];
#pragma unroll
            for (int j = 0; j < 8; ++j) uv[j] = *(const ushort4*)hp[j];
#pragma unroll
            for (int j = 0; j < 8; ++j) {
                acc.x = fmaf(we[j], bf2f(uv[j].x), acc.x);
                acc.y = fmaf(we[j], bf2f(uv[j].y), acc.y);
                acc.z = fmaf(we[j], bf2f(uv[j].z), acc.z);
                acc.w = fmaf(we[j], bf2f(uv[j].w), acc.w);
            }
        }
        LDS_FENCE();   // WAR guard: next chunk's weight phase overwrites w_lds
    }
    // head totals live on lanes sharing (lane&15)
    swp += __shfl_xor(swp, 16);
    swp += __shfl_xor(swp, 32);
    float inv = 1.0f / __shfl(swp, lane >> 2);   // head of this lane's col group
    float4 bv = *(const float4*)(bias + lane * 4);
    ushort4 o;
    o.x = f2bf(fmaxf(fmaf(acc.x, inv, bv.x), 0.f));
    o.y = f2bf(fmaxf(fmaf(acc.y, inv, bv.y), 0.f));
    o.z = f2bf(fmaxf(fmaf(acc.z, inv, bv.z), 0.f));
    o.w = f2bf(fmaxf(fmaf(acc.w, inv, bv.w), 0.f));
    *(ushort4*)(outb + (size_t)n * 256 + lane * 4) = o;
}

// ---------- fused mean-pool + final linear: one block per graph (B is bf16) ----------
__device__ __forceinline__ int lower_bound_i(const int* __restrict__ a, int n, int v) {
    int lo = 0, hi = n;
    while (lo < hi) {
        int mid = (lo + hi) >> 1;
        if (a[mid] < v) lo = mid + 1; else hi = mid;
    }
    return lo;
}

__global__ __launch_bounds__(1024) void k_pool_final(const ushort* __restrict__ Bb,
                                                     const int* __restrict__ batch,
                                                     const float* __restrict__ lw,
                                                     const float* __restrict__ lb,
                                                     float* __restrict__ out,
                                                     int N, int L) {
    __shared__ float psum[4][256];
    __shared__ float csum[256];
    int t = threadIdx.x;
    int c = t & 255, q = t >> 8;
    int g = blockIdx.x;
    int lo = lower_bound_i(batch, N, g);
    int hi = lower_bound_i(batch, N, g + 1);
    int len = hi - lo;
    int per = (len + 3) >> 2;
    int s0 = lo + q * per, s1 = min(hi, s0 + per);
    float acc = 0.f;
    for (int r = s0; r < s1; ++r) acc += bf2f(Bb[(size_t)r * 256 + c]);
    psum[q][c] = acc;
    __syncthreads();
    if (t < 256) csum[t] = psum[0][t] + psum[1][t] + psum[2][t] + psum[3][t];
    __syncthreads();
    int wave = t >> 6, lane = t & 63;
    if (wave < L) {
        int l = wave;
        float a = csum[lane] * lw[lane * L + l] +
                  csum[lane + 64] * lw[(lane + 64) * L + l] +
                  csum[lane + 128] * lw[(lane + 128) * L + l] +
                  csum[lane + 192] * lw[(lane + 192) * L + l];
#pragma unroll
        for (int off = 32; off >= 1; off >>= 1) a += __shfl_xor(a, off);
        if (lane == 0) out[g * L + l] = a / fmaxf((float)len, 1.0f) + lb[l];
    }
}

extern "C" void kernel_launch(void* const* d_in, const int* in_sizes, int n_in,
                              void* d_out, int out_size, void* d_ws, size_t ws_size,
                              hipStream_t stream) {
    const float* x   = (const float*)d_in[0];
    const int*   ei  = (const int*)d_in[1];
    const int*   bat = (const int*)d_in[2];
    const float* W1  = (const float*)d_in[3];
    const float* as1 = (const float*)d_in[4];
    const float* ad1 = (const float*)d_in[5];
    const float* b1  = (const float*)d_in[6];
    const float* W2  = (const float*)d_in[7];
    const float* as2 = (const float*)d_in[8];
    const float* ad2 = (const float*)d_in[9];
    const float* b2  = (const float*)d_in[10];
    const float* lw  = (const float*)d_in[11];
    const float* lb  = (const float*)d_in[12];
    float* out = (float*)d_out;

    const int N = in_sizes[2];        // 10000
    const int E = in_sizes[1] / 2;    // 320000
    const int G = 64, L = 10;
    const int Etot = E + N;
    const int NP = (N + 31) >> 5;     // partitions of 32 dsts (313)
    const int CE = (Etot + CSR_NB - 1) / CSR_NB;

    // workspace layout (A/B keep fp32-sized slots; used as bf16)
    float* A    = (float*)d_ws;              // [N,256] bf16 h1 then h2 (as ushort)
    float* B    = A + (size_t)N * 256;       // [N,256] bf16 out1 then out2 (as ushort)
    float* als1 = B + (size_t)N * 256;       // [N,16]
    float* ald1 = als1 + (size_t)N * 16;
    float* als2 = ald1 + (size_t)N * 16;     // [N]
    float* ald2 = als2 + N;
    int2* rowse = (int2*)(ald2 + N);         // [N] {start,end}
    int* col    = (int*)(rowse + N);         // [NP*CAP] strided segments
    int* tmp    = col + (size_t)NP * CSR_CAP;// [NP*CAP] packed (src<<5)|d5
    int* gcount = tmp + (size_t)NP * CSR_CAP;// [NP]
    ushort* Wt  = (ushort*)(gcount + NP);    // [256][256] bf16 W2 transposed
    ushort* Abf = (ushort*)A;
    ushort* Bbf = (ushort*)B;

    const int BS = 256;
    auto nb = [](int n, int b) { return (n + b - 1) / b; };
    int nodes4 = nb(N, 4);
    int rows16 = nb(N, 16);

    // ---- zero partition counters, then fused CSR-scatter + Wt-convert + gemm1 ----
    hipMemsetAsync(gcount, 0, NP * sizeof(int), stream);
    k_scatter_gemm1<<<CSR_NB + WT_NB + rows16, BS, 0, stream>>>(
        ei, E, N, NP, CE, gcount, tmp, x, W1, Abf, as1, ad1, als1, ald1, W2, Wt);
    k_csr_final<<<NP, BS, 0, stream>>>(tmp, gcount, rowse, col, N);

    // ---- layer 1 aggregate ----
    k_gather_h16<<<nodes4, BS, 0, stream>>>(rowse, col, Abf, als1, ald1, b1, Bbf, N);

    // ---- layer 2 (MFMA) ----
    k_gemm2_mfma<<<rows16, BS, 0, stream>>>(Bbf, Wt, Abf, as2, ad2, als2, ald2, N);
    k_gather_h1<<<nodes4, BS, 0, stream>>>(rowse, col, Abf, als2, ald2, b2, Bbf, N);

    // ---- fused pool + final linear ----
    k_pool_final<<<G, 1024, 0, stream>>>(Bbf, bat, lw, lb, out, N, L);
}